// Round 10
// baseline (421.927 us; speedup 1.0000x reference)
//
#include <hip/hip_runtime.h>
#include <hip/hip_bf16.h>

#define NN 50000
#define NE 800000
#define FIN 128
#define HC 256
#define NEG_SLOPE 0.2f
#define LOG2E 1.4426950408889634f

#define GEMM_BLOCKS 1564  // ceil(NN/64)*2  (64x128 tiles)
#define FUSED_BLOCKS 782  // ceil(NN/64)    (64-dst fused blocks)
#define NSCAT 3328        // 416 chunks x 8 XCD copies (chunk = 2048 entries)
#define NB_HIST 782       // ceil(NE/1024), 4 entries/thread
#define NB_W1 128         // FIN*HC/256
#define NB_W2 256         // HC*HC/256
#define ELLS 64           // ELL stride (max degree ~45 + pad4 <= 52 < 64)

typedef short bf16x8 __attribute__((ext_vector_type(8)));
typedef float f32x4 __attribute__((ext_vector_type(4)));

__device__ __forceinline__ unsigned short f2bf(float f) {
  unsigned u = __float_as_uint(f);
  u += 0x7fff + ((u >> 16) & 1);  // RTN-even
  return (unsigned short)(u >> 16);
}
__device__ __forceinline__ float bf2f(unsigned short s) {
  return __uint_as_float((unsigned)s << 16);
}
__device__ __forceinline__ float bflo(unsigned u) { return __uint_as_float(u << 16); }
__device__ __forceinline__ float bfhi(unsigned u) { return __uint_as_float(u & 0xffff0000u); }

// ---------------- fused prep: hist+rank + transpose/split W1,W2 + guards -------------
// counts zeroed by hipMemsetAsync before this launch. The hist atomicAdd's RETURN
// VALUE is the edge's rank within its dst row -> stored to rank[e] (deterministic
// ELL scatter: no atomics, no cursor array, no scans). Guard rows (one row BEFORE
// each gather table; a_s/a_s2 guards = -1e30) make poisoned pad entries (s = -1)
// contribute weight exp2(-1e30) = 0 with zero per-edge masking.
__global__ __launch_bounds__(256) void prep_hist(
    const float* __restrict__ W1, unsigned short* __restrict__ W1th,
    unsigned short* __restrict__ W1tl, const float* __restrict__ W2,
    unsigned short* __restrict__ W2th, unsigned short* __restrict__ W2tl,
    const int* __restrict__ ei, int* __restrict__ counts, int* __restrict__ rank,
    unsigned* __restrict__ gA, unsigned* __restrict__ gC,
    float* __restrict__ asg, float* __restrict__ asg2) {
  int b = blockIdx.x, t = threadIdx.x;
  if (b < NB_HIST) {
#pragma unroll
    for (int u = 0; u < 4; ++u) {
      int e = b * 1024 + u * 256 + t;
      if (e < NE) rank[e] = atomicAdd(&counts[ei[NE + e]], 1);
    }
  } else if (b < NB_HIST + NB_W1) {
    int j = (b - NB_HIST) * 256 + t;  // j = n*K+k, output-contiguous, K=128
    int n = j >> 7, k = j & 127;
    float v = W1[k * HC + n];
    unsigned short h = f2bf(v);
    W1th[j] = h;
    W1tl[j] = f2bf(v - bf2f(h));
  } else if (b < NB_HIST + NB_W1 + NB_W2) {
    int j = (b - NB_HIST - NB_W1) * 256 + t;  // K=256
    int n = j >> 8, k = j & 255;
    float v = W2[k * HC + n];
    unsigned short h = f2bf(v);
    W2th[j] = h;
    W2tl[j] = f2bf(v - bf2f(h));
  } else {
    // misc: zero gather-table guard rows (256 shorts = 128 uints each), coef guards
    if (t < 128) { gA[t] = 0; gC[t] = 0; }
    if (t < 8) { asg[t] = -1e30f; asg2[t] = -1e30f; }
  }
}

// ---------------- MFMA GEMM + fused coef, 64x128 tile (layer 1 only) -----------------
// Cb(bf16) = A_bf16 @ (Bh+Bl)^T(stored [N][K]); 2-term split.
// BK=32, stride-40 LDS (<=2-way banks, free), uint4 VGPR staging (round-6's
// async/BK=64 variant regressed — keep this form). A-staging loads fp32 X and
// converts f2bf in-register. Trailing blocks run the XCD-LOCAL, ATOMIC-FREE ELL
// scatter: pos = d*ELLS + rank[e]; sid%8 selects a dst range of 6250 so each
// XCD's ce write window stays L2-resident. Mapping-independent correctness.
__global__ __launch_bounds__(256) void gemm_coef(
    const float* __restrict__ Af,
    const unsigned short* __restrict__ Bth, const unsigned short* __restrict__ Btl,
    const float* __restrict__ att_s, const float* __restrict__ att_d,
    unsigned short* __restrict__ Cb, float* __restrict__ a_s,
    float* __restrict__ a_d, int M, int K,
    const int* __restrict__ ei, const int* __restrict__ cnts,
    const int* __restrict__ rank, int2* __restrict__ ce, int gemmN) {
  __shared__ unsigned short sA[64 * 40];
  __shared__ unsigned short sBh[128 * 40];
  __shared__ unsigned short sBl[128 * 40];
  __shared__ float sCS[64][4];
  __shared__ float sCD[64][4];

  int bid = blockIdx.x, t = threadIdx.x;
  if (bid >= gemmN) {
    int sid = bid - gemmN;
    int x = sid & 7;        // dst range = presumed XCD of this block
    int c = sid >> 3;       // chunk over the edge list
#pragma unroll
    for (int u = 0; u < 8; ++u) {
      int e = c * 2048 + u * 256 + t;
      if (e < NE + NN) {
        int d = (e < NE) ? ei[NE + e] : e - NE;
        if ((unsigned)d / 6250u == (unsigned)x) {
          if (e < NE) {
            ce[d * ELLS + rank[e]] = make_int2(ei[e], e);
          } else {
            int cnt = cnts[d];
            int pad4 = (cnt + 4) & ~3;  // loop bound in gathers
            ce[d * ELLS + cnt] = make_int2(d, -1);  // self-loop
            for (int p = cnt + 1; p < pad4; ++p)
              ce[d * ELLS + p] = make_int2(-1, -1);  // poison pads
          }
        }
      }
    }
    return;
  }

  int w = t >> 6, lane = t & 63;
  int quad = lane >> 4, lrow = lane & 15;
  int m0 = (bid >> 1) * 64, n0 = (bid & 1) * 128;
  int rm = (w & 1) * 32, cn = (w >> 1) * 64;

  f32x4 acc[2][4] = {};

  for (int k0 = 0; k0 < K; k0 += 32) {
    // stage A: fp32 X convert path
    {
      int row = t >> 2, q = t & 3;
      int gm = m0 + row;
      if (gm >= M) gm = M - 1;
      const float4* xp = (const float4*)(Af + (size_t)gm * K + k0 + q * 8);
      float4 f0 = xp[0], f1 = xp[1];
      uint4 h;
      h.x = (unsigned)f2bf(f0.x) | ((unsigned)f2bf(f0.y) << 16);
      h.y = (unsigned)f2bf(f0.z) | ((unsigned)f2bf(f0.w) << 16);
      h.z = (unsigned)f2bf(f1.x) | ((unsigned)f2bf(f1.y) << 16);
      h.w = (unsigned)f2bf(f1.z) | ((unsigned)f2bf(f1.w) << 16);
      *(uint4*)(sA + row * 40 + q * 8) = h;
    }
    // stage B: 128 rows x 4 chunks = 512 -> 2/thread
#pragma unroll
    for (int i = 0; i < 2; ++i) {
      int idx = t + i * 256;
      int row = idx >> 2, q = idx & 3;
      size_t gbx = (size_t)(n0 + row) * K + k0 + q * 8;
      *(uint4*)(sBh + row * 40 + q * 8) = *(const uint4*)(Bth + gbx);
      *(uint4*)(sBl + row * 40 + q * 8) = *(const uint4*)(Btl + gbx);
    }
    __syncthreads();

    bf16x8 fa[2];
#pragma unroll
    for (int mi = 0; mi < 2; ++mi)
      fa[mi] = *(const bf16x8*)(sA + (rm + mi * 16 + lrow) * 40 + quad * 8);
#pragma unroll
    for (int ni = 0; ni < 4; ++ni) {
      bf16x8 fbh = *(const bf16x8*)(sBh + (cn + ni * 16 + lrow) * 40 + quad * 8);
      bf16x8 fbl = *(const bf16x8*)(sBl + (cn + ni * 16 + lrow) * 40 + quad * 8);
#pragma unroll
      for (int mi = 0; mi < 2; ++mi) {
        acc[mi][ni] = __builtin_amdgcn_mfma_f32_16x16x32_bf16(fa[mi], fbh, acc[mi][ni], 0, 0, 0);
        acc[mi][ni] = __builtin_amdgcn_mfma_f32_16x16x32_bf16(fa[mi], fbl, acc[mi][ni], 0, 0, 0);
      }
    }
    __syncthreads();
  }

  float vs[4], vd[4];
#pragma unroll
  for (int ni = 0; ni < 4; ++ni) {
    int gn = n0 + cn + ni * 16 + lrow;
    vs[ni] = att_s[gn] * LOG2E;
    vd[ni] = att_d[gn] * LOG2E;
  }
  int h4e = cn >> 5;

  // C/D layout: col = lane&15, row = quad*4 + reg  [m89-verified]
#pragma unroll
  for (int mi = 0; mi < 2; ++mi) {
#pragma unroll
    for (int r = 0; r < 4; ++r) {
      int lr = rm + mi * 16 + quad * 4 + r;
      int gm = m0 + lr;
      if (gm < M) {
#pragma unroll
        for (int ni = 0; ni < 4; ++ni) {
          int gn = n0 + cn + ni * 16 + lrow;
          Cb[(size_t)gm * HC + gn] = f2bf(acc[mi][ni][r]);
        }
      }
      float pse = acc[mi][0][r] * vs[0] + acc[mi][1][r] * vs[1];
      float pso = acc[mi][2][r] * vs[2] + acc[mi][3][r] * vs[3];
      float pde = acc[mi][0][r] * vd[0] + acc[mi][1][r] * vd[1];
      float pdo = acc[mi][2][r] * vd[2] + acc[mi][3][r] * vd[3];
#pragma unroll
      for (int off = 1; off <= 8; off <<= 1) {
        pse += __shfl_xor(pse, off);
        pso += __shfl_xor(pso, off);
        pde += __shfl_xor(pde, off);
        pdo += __shfl_xor(pdo, off);
      }
      if (lrow == 0) {
        sCS[lr][h4e] = pse;
        sCS[lr][h4e + 1] = pso;
        sCD[lr][h4e] = pde;
        sCD[lr][h4e + 1] = pdo;
      }
    }
  }
  __syncthreads();
  if (t < 64) {
    int gm = m0 + t;
    if (gm < M) {
      int o = (n0 >> 5);  // 0 or 4
      *(float4*)(a_s + (size_t)gm * 8 + o) = *(const float4*)&sCS[t][0];
      *(float4*)(a_d + (size_t)gm * 8 + o) = *(const float4*)&sCD[t][0];
    }
  }
}

// ---------------- FUSED agg1 + gemm2: 1024 threads, 64 dsts/block --------------------
// Phase 1 (gather): 16 waves x 4 dsts, identical math/layout to the proven agg loop
//   (one dst per wave at a time, 4-edge batches, poisoned pads via guard rows).
//   h1 rows land in LDS as bf16 — NEVER written to HBM (saves 25.6MB wr + 25.6MB rd,
//   and the separate gemm2 launch).
// Phase 2 (GEMM): 4x4 wave grid, 64x256 output tile, BK=32, proven stride-40
//   B-staging and m89-verified C/D layout — bit-identical math to gemm_coef.
// Rationale: agg1 is latency-bound (2x off BW roofline, memory pipes half idle,
//   four structural variants all 71-72us); gemm2 is MFMA/LDS-bound with idle HBM.
//   Co-resident gather-phase and GEMM-phase blocks fill both pipes.
// Outputs go to SEPARATE buffers (hbC, a_s2/a_d2): other blocks still gather-read
//   hbA/a_s concurrently. LDS 77KB -> 2 blocks/CU (1024-thread-limited anyway).
__global__ __launch_bounds__(1024) void agg_gemm(
    const unsigned short* __restrict__ htb, const float* __restrict__ a_s,
    const float* __restrict__ a_d, const int* __restrict__ cnts,
    const int2* __restrict__ ce, const float* __restrict__ bias,
    const unsigned short* __restrict__ Bth, const unsigned short* __restrict__ Btl,
    const float* __restrict__ att_s, const float* __restrict__ att_d,
    unsigned short* __restrict__ Cb, float* __restrict__ a_s2,
    float* __restrict__ a_d2) {
  __shared__ unsigned short sH[64 * 264];   // h1 tile bf16, stride 264 (2-way banks)
  __shared__ unsigned short sBh[256 * 40];  // W2 high split, BK=32 slab
  __shared__ unsigned short sBl[256 * 40];
  __shared__ float sCS[64][8];
  __shared__ float sCD[64][8];

  int t = threadIdx.x;
  int w = t >> 6, lane = t & 63;
  int m0 = blockIdx.x * 64;

  // ---- phase 1: gather (wave w owns local rows 4w..4w+3) ----
  {
    int l = lane;
    int hh = l >> 3;
    const uint2* ht2 = (const uint2*)htb;
    float4 bi = *(const float4*)(bias + l * 4);
    for (int i = 0; i < 4; ++i) {
      int lr = 4 * w + i;
      int d = m0 + lr;
      if (d < NN) {
        float adh = a_d[d * 8 + hh];
        int r0 = d * ELLS;
        int r1 = r0 + ((cnts[d] + 4) & ~3);  // +1 self-loop, padded to x4
        float denom = 0.f;
        float4 acc = {0.f, 0.f, 0.f, 0.f};
        for (int r = r0; r < r1; r += 4) {
          const int4* cp = (const int4*)(ce + r);
          int4 c01 = cp[0], c23 = cp[1];
          int s[4] = {c01.x, c01.z, c23.x, c23.z};
          float as_[4];
          uint2 q[4];
#pragma unroll
          for (int j = 0; j < 4; ++j) {
            as_[j] = a_s[s[j] * 8 + hh];
            q[j] = ht2[s[j] * 64 + l];
          }
#pragma unroll
          for (int j = 0; j < 4; ++j) {
            float e = as_[j] + adh;
            e = fmaxf(e, NEG_SLOPE * e);
            float wgt = exp2f(e);
            denom += wgt;
            acc.x += wgt * bflo(q[j].x);
            acc.y += wgt * bfhi(q[j].x);
            acc.z += wgt * bflo(q[j].y);
            acc.w += wgt * bfhi(q[j].y);
          }
        }
        float dv = 1.f / denom;
        float4 o;
        o.x = fmaxf(fmaf(acc.x, dv, bi.x), 0.f);
        o.y = fmaxf(fmaf(acc.y, dv, bi.y), 0.f);
        o.z = fmaxf(fmaf(acc.z, dv, bi.z), 0.f);
        o.w = fmaxf(fmaf(acc.w, dv, bi.w), 0.f);
        uint2 pb;
        pb.x = (unsigned)f2bf(o.x) | ((unsigned)f2bf(o.y) << 16);
        pb.y = (unsigned)f2bf(o.z) | ((unsigned)f2bf(o.w) << 16);
        *(uint2*)(sH + lr * 264 + l * 4) = pb;  // lane l owns channels 4l..4l+3
      }
    }
  }
  __syncthreads();

  // ---- phase 2: 64x256 GEMM from LDS h1 tile ----
  int wr = w >> 2, wc = w & 3;  // 4x4 wave grid: rows 16wr.., cols 64wc..
  int quad = lane >> 4, lrow = lane & 15;

  f32x4 acc[4] = {};

  for (int k0 = 0; k0 < HC; k0 += 32) {
    // stage B slab: 1024 threads <-> 1024 uint4 chunks (256 rows x 4)
    {
      int row = t >> 2, q = t & 3;
      size_t gbx = (size_t)row * HC + k0 + q * 8;
      *(uint4*)(sBh + row * 40 + q * 8) = *(const uint4*)(Bth + gbx);
      *(uint4*)(sBl + row * 40 + q * 8) = *(const uint4*)(Btl + gbx);
    }
    __syncthreads();

    bf16x8 fa = *(const bf16x8*)(sH + (wr * 16 + lrow) * 264 + k0 + quad * 8);
#pragma unroll
    for (int ni = 0; ni < 4; ++ni) {
      int brow = wc * 64 + ni * 16 + lrow;
      bf16x8 fbh = *(const bf16x8*)(sBh + brow * 40 + quad * 8);
      bf16x8 fbl = *(const bf16x8*)(sBl + brow * 40 + quad * 8);
      acc[ni] = __builtin_amdgcn_mfma_f32_16x16x32_bf16(fa, fbh, acc[ni], 0, 0, 0);
      acc[ni] = __builtin_amdgcn_mfma_f32_16x16x32_bf16(fa, fbl, acc[ni], 0, 0, 0);
    }
    __syncthreads();
  }

  // epilogue: identical structure to gemm_coef (cols wc*64.., head pair 2wc)
  float vs[4], vd[4];
#pragma unroll
  for (int ni = 0; ni < 4; ++ni) {
    int gn = wc * 64 + ni * 16 + lrow;
    vs[ni] = att_s[gn] * LOG2E;
    vd[ni] = att_d[gn] * LOG2E;
  }
  int h4e = wc * 2;

#pragma unroll
  for (int r = 0; r < 4; ++r) {
    int lr = wr * 16 + quad * 4 + r;
    int gm = m0 + lr;
    if (gm < NN) {
#pragma unroll
      for (int ni = 0; ni < 4; ++ni) {
        int gn = wc * 64 + ni * 16 + lrow;
        Cb[(size_t)gm * HC + gn] = f2bf(acc[ni][r]);
      }
    }
    float pse = acc[0][r] * vs[0] + acc[1][r] * vs[1];
    float pso = acc[2][r] * vs[2] + acc[3][r] * vs[3];
    float pde = acc[0][r] * vd[0] + acc[1][r] * vd[1];
    float pdo = acc[2][r] * vd[2] + acc[3][r] * vd[3];
#pragma unroll
    for (int off = 1; off <= 8; off <<= 1) {
      pse += __shfl_xor(pse, off);
      pso += __shfl_xor(pso, off);
      pde += __shfl_xor(pde, off);
      pdo += __shfl_xor(pdo, off);
    }
    if (lrow == 0) {
      sCS[lr][h4e] = pse;
      sCS[lr][h4e + 1] = pso;
      sCD[lr][h4e] = pde;
      sCD[lr][h4e + 1] = pdo;
    }
  }
  __syncthreads();
  if (t < 128) {
    int row = t >> 1, half = t & 1;
    int gm = m0 + row;
    if (gm < NN) {
      *(float4*)(a_s2 + (size_t)gm * 8 + half * 4) = *(const float4*)&sCS[row][half * 4];
      *(float4*)(a_d2 + (size_t)gm * 8 + half * 4) = *(const float4*)&sCD[row][half * 4];
    }
  }
}

// ---------------- aggregation (layer 2): one dst per wave, ELL rows, 4-edge ----------
// Proven floor kernel (71-72us across four structural variants — do not touch).
__global__ __launch_bounds__(256) void agg_kernel(
    const unsigned short* __restrict__ htb, const float* __restrict__ a_s,
    const float* __restrict__ a_d, const int* __restrict__ cnts,
    const int2* __restrict__ ce, const float* __restrict__ bias,
    unsigned short* __restrict__ outb,
    const float* __restrict__ Wn, const float* __restrict__ bn,
    float* __restrict__ outn) {
  int d = blockIdx.x * 4 + (threadIdx.x >> 6);
  if (d >= NN) return;
  int l = threadIdx.x & 63;
  int hh = l >> 3;
  const uint2* ht2 = (const uint2*)htb;
  float adh = a_d[d * 8 + hh];
  int r0 = d * ELLS;
  int r1 = r0 + ((cnts[d] + 4) & ~3);
  float denom = 0.f;
  float4 acc = {0.f, 0.f, 0.f, 0.f};
  for (int r = r0; r < r1; r += 4) {
    const int4* cp = (const int4*)(ce + r);
    int4 c01 = cp[0], c23 = cp[1];
    int s[4] = {c01.x, c01.z, c23.x, c23.z};
    float as_[4];
    uint2 q[4];
#pragma unroll
    for (int j = 0; j < 4; ++j) {
      as_[j] = a_s[s[j] * 8 + hh];
      q[j] = ht2[s[j] * 64 + l];
    }
#pragma unroll
    for (int j = 0; j < 4; ++j) {
      float e = as_[j] + adh;
      e = fmaxf(e, NEG_SLOPE * e);
      float w = exp2f(e);
      denom += w;
      acc.x += w * bflo(q[j].x);
      acc.y += w * bfhi(q[j].x);
      acc.z += w * bflo(q[j].y);
      acc.w += w * bfhi(q[j].y);
    }
  }
  float dv = 1.f / denom;
  float4 bi = *(const float4*)(bias + l * 4);
  float4 o;
  o.x = fmaxf(fmaf(acc.x, dv, bi.x), 0.f);
  o.y = fmaxf(fmaf(acc.y, dv, bi.y), 0.f);
  o.z = fmaxf(fmaf(acc.z, dv, bi.z), 0.f);
  o.w = fmaxf(fmaf(acc.w, dv, bi.w), 0.f);
  uint2 pb;
  pb.x = (unsigned)f2bf(o.x) | ((unsigned)f2bf(o.y) << 16);
  pb.y = (unsigned)f2bf(o.z) | ((unsigned)f2bf(o.w) << 16);
  ((uint2*)outb)[d * 64 + l] = pb;
  if (outn) {
    float4 wv = *(const float4*)(Wn + l * 4);
    float p = o.x * wv.x + o.y * wv.y + o.z * wv.z + o.w * wv.w;
#pragma unroll
    for (int off = 1; off <= 32; off <<= 1) p += __shfl_xor(p, off);
    if (l == 0) outn[d] = p + bn[0];
  }
}

// ---------------- edge predictions: 16-lane group per edge, 4-edge unroll ------------
__global__ __launch_bounds__(256) void edge_pred_kernel(
    const unsigned short* __restrict__ h2b, const int* __restrict__ cnts,
    const int2* __restrict__ ce, const float* __restrict__ We,
    const float* __restrict__ be, float* __restrict__ out) {
  int d = blockIdx.x * 4 + (threadIdx.x >> 6);
  if (d >= NN) return;
  int lane = threadIdx.x & 63;
  int g = lane >> 4, l = lane & 15;
  float b = be[0];
  const uint4* h24 = (const uint4*)h2b;

  uint4 qd0 = h24[d * 32 + l * 2], qd1 = h24[d * 32 + l * 2 + 1];
  float wd[16];
  {
    const float4* wep = (const float4*)(We + l * 16);
    float4 w0 = wep[0], w1 = wep[1], w2 = wep[2], w3 = wep[3];
    wd[0] = bflo(qd0.x) * w0.x;  wd[1] = bfhi(qd0.x) * w0.y;
    wd[2] = bflo(qd0.y) * w0.z;  wd[3] = bfhi(qd0.y) * w0.w;
    wd[4] = bflo(qd0.z) * w1.x;  wd[5] = bfhi(qd0.z) * w1.y;
    wd[6] = bflo(qd0.w) * w1.z;  wd[7] = bfhi(qd0.w) * w1.w;
    wd[8] = bflo(qd1.x) * w2.x;  wd[9] = bfhi(qd1.x) * w2.y;
    wd[10] = bflo(qd1.y) * w2.z; wd[11] = bfhi(qd1.y) * w2.w;
    wd[12] = bflo(qd1.z) * w3.x; wd[13] = bfhi(qd1.z) * w3.y;
    wd[14] = bflo(qd1.w) * w3.z; wd[15] = bfhi(qd1.w) * w3.w;
  }

  int r0 = d * ELLS, r1 = r0 + cnts[d];
  for (int r = r0; r < r1; r += 16) {
    int ss[4], id[4];
#pragma unroll
    for (int j = 0; j < 4; ++j) {
      int rr = r + 4 * j + g;
      ss[j] = 0; id[j] = -1;
      if (rr < r1) { int2 p = ce[rr]; ss[j] = p.x; id[j] = p.y; }
    }
    uint4 a0[4], a1[4];
#pragma unroll
    for (int j = 0; j < 4; ++j) {
      a0[j] = h24[ss[j] * 32 + l * 2];
      a1[j] = h24[ss[j] * 32 + l * 2 + 1];
    }
    float p[4];
#pragma unroll
    for (int j = 0; j < 4; ++j) {
      p[j] = bflo(a0[j].x) * wd[0] + bfhi(a0[j].x) * wd[1] + bflo(a0[j].y) * wd[2] +
             bfhi(a0[j].y) * wd[3] + bflo(a0[j].z) * wd[4] + bfhi(a0[j].z) * wd[5] +
             bflo(a0[j].w) * wd[6] + bfhi(a0[j].w) * wd[7] + bflo(a1[j].x) * wd[8] +
             bfhi(a1[j].x) * wd[9] + bflo(a1[j].y) * wd[10] + bfhi(a1[j].y) * wd[11] +
             bflo(a1[j].z) * wd[12] + bfhi(a1[j].z) * wd[13] + bflo(a1[j].w) * wd[14] +
             bfhi(a1[j].w) * wd[15];
#pragma unroll
      for (int off = 1; off <= 8; off <<= 1) p[j] += __shfl_xor(p[j], off);
    }
    if (l == 0) {
#pragma unroll
      for (int j = 0; j < 4; ++j)
        if (id[j] >= 0) out[id[j]] = p[j] + b;
    }
  }
}

extern "C" void kernel_launch(void* const* d_in, const int* in_sizes, int n_in,
                              void* d_out, int out_size, void* d_ws, size_t ws_size,
                              hipStream_t stream) {
  const float* x  = (const float*)d_in[0];
  const int* ei   = (const int*)d_in[1];
  const float* W1 = (const float*)d_in[3];
  const float* as1 = (const float*)d_in[4];
  const float* ad1 = (const float*)d_in[5];
  const float* b1 = (const float*)d_in[6];
  const float* W2 = (const float*)d_in[7];
  const float* as2 = (const float*)d_in[8];
  const float* ad2 = (const float*)d_in[9];
  const float* b2 = (const float*)d_in[10];
  const float* We = (const float*)d_in[11];
  const float* be = (const float*)d_in[12];
  const float* Wn = (const float*)d_in[13];
  const float* bn = (const float*)d_in[14];
  float* out = (float*)d_out;

  char* wsp = (char*)d_ws;
  auto alloc = [&](size_t bytes) {
    char* p = wsp;
    wsp += (bytes + 255) & ~(size_t)255;
    return p;
  };
  // gather tables get one guard row (256 shorts) BEFORE the table (s=-1 pads).
  // hbB ALIASES hbA: hbA's last reader is agg_gemm; agg2 (writer of hbB) reads
  // only hbC — kernels are stream-serial, so no overlap window. Keeps workspace
  // at ~87MB (round-8's proven ~110MB budget; round-9's 113MB was the one
  // untested growth when the container died).
  unsigned short* hbAr = (unsigned short*)alloc((size_t)(NN + 1) * HC * 2);
  unsigned short* hbA = hbAr + HC;   // gemm1 out (fused kernel gathers from here)
  unsigned short* hbCr = (unsigned short*)alloc((size_t)(NN + 1) * HC * 2);
  unsigned short* hbC = hbCr + HC;   // fused out (agg2 gathers from here)
  unsigned short* hbB = hbA;         // agg2 out (edge_pred gathers from here) — alias
  float* a_sr = (float*)alloc((size_t)(8 + NN * 8) * 4);
  float* a_s = a_sr + 8;             // layer-1 coefs, guard -1e30
  float* a_d = (float*)alloc((size_t)NN * 8 * 4);
  float* a_s2r = (float*)alloc((size_t)(8 + NN * 8) * 4);
  float* a_s2 = a_s2r + 8;           // layer-2 coefs, guard -1e30
  float* a_d2 = (float*)alloc((size_t)NN * 8 * 4);
  int2* ce = (int2*)alloc((size_t)NN * ELLS * 8);  // ELL (src, edge-id), 25.6 MB
  int* counts = (int*)alloc((size_t)NN * 4);
  int* rank = (int*)alloc((size_t)NE * 4);
  unsigned short* W1th = (unsigned short*)alloc((size_t)FIN * HC * 2);
  unsigned short* W1tl = (unsigned short*)alloc((size_t)FIN * HC * 2);
  unsigned short* W2th = (unsigned short*)alloc((size_t)HC * HC * 2);
  unsigned short* W2tl = (unsigned short*)alloc((size_t)HC * HC * 2);

  // zero hist counters (rank & ce fully written by prep/scatter — no init needed)
  hipMemsetAsync(counts, 0, (size_t)NN * 4, stream);

  // fused: histogram+rank + W transposes + guard-row init
  prep_hist<<<NB_HIST + NB_W1 + NB_W2 + 1, 256, 0, stream>>>(
      W1, W1th, W1tl, W2, W2th, W2tl, ei, counts, rank,
      (unsigned*)hbAr, (unsigned*)hbCr, a_sr, a_s2r);

  // layer 1 gemm+coef (fp32-A convert path), ELL scatter in TRAILING blocks
  gemm_coef<<<GEMM_BLOCKS + NSCAT, 256, 0, stream>>>(
      x, W1th, W1tl, as1, ad1, hbA, a_s, a_d,
      NN, FIN, ei, counts, rank, ce, GEMM_BLOCKS);

  // FUSED agg1 + gemm2: gather h1 into LDS, MFMA x W2, emit hbC + layer-2 coefs
  agg_gemm<<<FUSED_BLOCKS, 1024, 0, stream>>>(
      hbA, a_s, a_d, counts, ce, b1, W2th, W2tl, as2, ad2, hbC, a_s2, a_d2);

  // layer-2 aggregation (node_pred fused into epilogue)
  agg_kernel<<<NN / 4, 256, 0, stream>>>(hbC, a_s2, a_d2, counts, ce, b2, hbB,
                                         Wn, bn, out + NE);

  // edge predictions
  edge_pred_kernel<<<NN / 4, 256, 0, stream>>>(hbB, counts, ce, We, be, out);
}